// Round 2
// baseline (774.320 us; speedup 1.0000x reference)
//
#include <hip/hip_runtime.h>

// RelPosEmbedder: out[p,c] = tok[p,:42] @ W[66:108,c] + W[d_res,c] + ent*W[108,c] + W[109+d_chain,c]
// fp32 in/out (per reference dtypes); bf16 MFMA internally (threshold is bf16-scale).

typedef __attribute__((ext_vector_type(8))) short short8;
typedef __attribute__((ext_vector_type(4))) float floatx4;

#define NSEQ    1024
#define NTOK    42
#define CZ      128
#define CHUNK   64          // pairs per chunk
#define NCHUNK  8           // chunks per block -> 512 pairs/block
#define THREADS 256
#define TOK_DW  21          // packed-bf16 dwords per pair row (42 elems)
#define LDS_AW  36          // uints per padded A row (42 data + 22 K-pad + 8 bank-pad bf16)
#define NGROWS  73          // gather rows staged in LDS: 0..65 (res), 108 (ent), 109..114 (chain)

__device__ __forceinline__ unsigned short f2bf(float f) {
    union { float f; unsigned int i; } v; v.f = f;
    unsigned int i = v.i;
    return (unsigned short)((i + 0x7fffu + ((i >> 16) & 1u)) >> 16);   // RNE
}
__device__ __forceinline__ unsigned int packbf2(float x, float y) {
    return ((unsigned int)f2bf(y) << 16) | (unsigned int)f2bf(x);
}

__global__ __launch_bounds__(THREADS) void relpos_kernel(
    const float* __restrict__ tok,   // [N*N, 42] f32
    const float* __restrict__ W,     // [115, 128] f32
    const int* __restrict__ asym,
    const int* __restrict__ sym,
    const int* __restrict__ eid,
    const int* __restrict__ res,
    float* __restrict__ out)         // [N*N, 128] f32
{
    __shared__ __align__(16) unsigned int lds_Au[CHUNK * LDS_AW];  // A tile, packed bf16
    __shared__ float lds_W[NGROWS * CZ];                           // gather rows, fp32
    __shared__ int lds_flags[CHUNK];

    const int tid  = threadIdx.x;
    const int lane = tid & 63;
    const int wv   = tid >> 6;
    const int n    = lane & 15;   // MFMA col within 16-tile / A row m
    const int q    = lane >> 4;   // quad

    // ---- one-time: stage gather rows (fp32) into LDS ----
    for (int u = tid; u < NGROWS * CZ; u += THREADS) {
        int row = u >> 7;
        int wrow = row + (row >= 66 ? 42 : 0);   // 66->108, 67..72 -> 109..114
        lds_W[u] = W[wrow * CZ + (u & 127)];
    }

    // ---- one-time: B fragments (W rows 66..107 as bf16, K zero-padded to 64) ----
    // B layout (16x16x32): lane holds B[k = ks*32 + q*8 + j][n = lane&15]
    short8 bfrag[2][8];
    #pragma unroll
    for (int ks = 0; ks < 2; ++ks) {
        #pragma unroll
        for (int nt = 0; nt < 8; ++nt) {
            short8 b;
            #pragma unroll
            for (int j = 0; j < 8; ++j) {
                int k = ks * 32 + q * 8 + j;
                b[j] = (k < NTOK) ? (short)f2bf(W[(66 + k) * CZ + nt * 16 + n]) : (short)0;
            }
            bfrag[ks][nt] = b;
        }
    }

    const int pblock = blockIdx.x * (CHUNK * NCHUNK);

    for (int ch = 0; ch < NCHUNK; ++ch) {
        const int p0 = pblock + ch * CHUNK;
        __syncthreads();  // protect LDS A/flags reuse across iterations

        // ---- stage A tile: 64 pairs x 42 f32, convert to packed bf16 ----
        const float2* tokv = (const float2*)tok + (size_t)p0 * TOK_DW;
        for (int u = tid; u < CHUNK * TOK_DW; u += THREADS) {
            float2 d = tokv[u];
            int pr = u / TOK_DW;
            int cu = u - pr * TOK_DW;
            lds_Au[pr * LDS_AW + cu] = packbf2(d.x, d.y);
        }
        // zero K-pad: bf16 cols 42..63 = uint cols 21..31
        for (int u = tid; u < CHUNK * 11; u += THREADS) {
            int pr = u / 11;
            lds_Au[pr * LDS_AW + 21 + (u - pr * 11)] = 0;
        }
        // ---- per-pair gather flags ----
        if (tid < CHUNK) {
            int p = p0 + tid;
            int i = p >> 10, j = p & (NSEQ - 1);
            bool cs = asym[i] == asym[j];
            bool es = eid[i] == eid[j];
            int ro = res[i] - res[j] + 32;
            ro = ro < 0 ? 0 : (ro > 64 ? 64 : ro);
            int dres = cs ? ro : 65;                 // gather row 0..65
            int co = sym[i] - sym[j] + 2;
            co = co < 0 ? 0 : (co > 4 ? 4 : co);
            int dch = (cs || !es) ? 5 : co;          // gather row 67+dch
            lds_flags[tid] = dres | (dch << 8) | ((es ? 1 : 0) << 16);
        }
        __syncthreads();

        // ---- MFMA: 16 pairs x 128 channels per wave ----
        // A layout: lane holds A[m = lane&15][k = ks*32 + q*8 + j]
        const unsigned short* arow = (const unsigned short*)&lds_Au[(wv * 16 + n) * LDS_AW];
        short8 a0 = *(const short8*)(arow + q * 8);
        short8 a1 = *(const short8*)(arow + 32 + q * 8);
        floatx4 acc[8];
        #pragma unroll
        for (int nt = 0; nt < 8; ++nt) {
            floatx4 z = {0.f, 0.f, 0.f, 0.f};
            z = __builtin_amdgcn_mfma_f32_16x16x32_bf16(a0, bfrag[0][nt], z, 0, 0, 0);
            z = __builtin_amdgcn_mfma_f32_16x16x32_bf16(a1, bfrag[1][nt], z, 0, 0, 0);
            acc[nt] = z;
        }

        // ---- epilogue: add gathered rows (fp32, from LDS), store fp32 ----
        // C/D layout: col = lane&15 (per nt tile), row = q*4 + r
        #pragma unroll
        for (int r = 0; r < 4; ++r) {
            int pl = wv * 16 + q * 4 + r;
            int fl = lds_flags[pl];
            const float* wres = lds_W + (fl & 0xff) * CZ;
            const float* wch  = lds_W + (67 + ((fl >> 8) & 0xff)) * CZ;
            float entf = (fl >> 16) ? 1.0f : 0.0f;
            const float* went = lds_W + 66 * CZ;
            size_t obase = ((size_t)(p0 + pl)) * CZ;
            #pragma unroll
            for (int nt = 0; nt < 8; ++nt) {
                int c = nt * 16 + n;
                out[obase + c] = acc[nt][r] + wres[c] + entf * went[c] + wch[c];
            }
        }
    }
}

extern "C" void kernel_launch(void* const* d_in, const int* in_sizes, int n_in,
                              void* d_out, int out_size, void* d_ws, size_t ws_size,
                              hipStream_t stream) {
    const float* tok = (const float*)d_in[0];   // rel_tok_feat f32
    const float* W   = (const float*)d_in[1];   // W f32
    const int* asym  = (const int*)d_in[2];
    const int* sym   = (const int*)d_in[3];
    const int* eid   = (const int*)d_in[4];
    const int* res   = (const int*)d_in[5];
    float* out = (float*)d_out;

    const int npairs = NSEQ * NSEQ;
    const int grid = npairs / (CHUNK * NCHUNK);  // 2048 blocks
    hipLaunchKernelGGL(relpos_kernel, dim3(grid), dim3(THREADS), 0, stream,
                       tok, W, asym, sym, eid, res, out);
}